// Round 1
// baseline (6233.609 us; speedup 1.0000x reference)
//
#include <hip/hip_runtime.h>
#include <math.h>

// Problem constants
#define B    64
#define C    128
#define H    32
#define W    32
#define HW   1024          // H*W
#define OUTC 640           // 5*C
#define PS   37            // padded plane leading dim (halo 2 each side = 36, +1 to break bank aliasing)
#define NSKIP (B*C*HW)     // 8388608
#define NW    (8*C*C*9)    // 1179648 per weight array

// ws layout (in floats)
#define ALPHA_OFF 0                    // 40 floats of softmaxed alphas
#define S0_OFF    64
#define S1_OFF    (S0_OFF + NSKIP)
#define W3_OFF    (S1_OFF + NSKIP)     // alpha1-scaled conv3 weights
#define WD3_OFF   (W3_OFF + NW)        // alpha2-scaled dil3 weights
// total = 19,136,576 floats = 76.5 MB of workspace

// ---------------------------------------------------------------------------
// Prep: softmax(alphas) -> ws[0..40); scale w3 by a1, wd3 by a2 into ws.
// ---------------------------------------------------------------------------
__global__ __launch_bounds__(256) void prep_kernel(
    const float* __restrict__ alphas, const float* __restrict__ w3,
    const float* __restrict__ wd3, float* __restrict__ ws) {
  __shared__ float as[40];
  int tid = threadIdx.x;
  if (tid < 8) {
    float v[5];
    float m = -1e30f;
    for (int j = 0; j < 5; j++) { v[j] = alphas[tid * 5 + j]; m = fmaxf(m, v[j]); }
    float s = 0.f;
    for (int j = 0; j < 5; j++) { v[j] = __expf(v[j] - m); s += v[j]; }
    float inv = 1.f / s;
    for (int j = 0; j < 5; j++) as[tid * 5 + j] = v[j] * inv;
  }
  __syncthreads();
  if (blockIdx.x == 0 && tid < 40) ws[ALPHA_OFF + tid] = as[tid];
  int stride = gridDim.x * blockDim.x;
  for (int i = blockIdx.x * blockDim.x + tid; i < 2 * NW; i += stride) {
    if (i < NW) {
      int o = i / (C * C * 9);
      ws[W3_OFF + i] = as[o * 5 + 1] * w3[i];
    } else {
      int j = i - NW;
      int o = j / (C * C * 9);
      ws[WD3_OFF + j] = as[o * 5 + 2] * wd3[j];
    }
  }
}

// ---------------------------------------------------------------------------
// Preprocess 1x1 convs: s0 = in0 * wp0, s1 = in1 * wp1   (NCHW, OIHW)
// grid (64, 8, 2), block 256.  Each block: one b, 16 co, all 1024 hw.
// ---------------------------------------------------------------------------
__global__ __launch_bounds__(256) void pre_kernel(
    const float* __restrict__ in0, const float* __restrict__ in1,
    const float* __restrict__ wp0, const float* __restrict__ wp1,
    float* __restrict__ ws) {
  int which = blockIdx.z;
  const float* in = which ? in1 : in0;
  const float* wp = which ? wp1 : wp0;
  float* out = ws + (which ? S1_OFF : S0_OFF);
  int b = blockIdx.x;
  int cg = blockIdx.y;            // 8 groups of 16 co
  int t = threadIdx.x;
  int hw0 = t * 4;

  float4 acc[16];
  #pragma unroll
  for (int k = 0; k < 16; k++) acc[k] = make_float4(0.f, 0.f, 0.f, 0.f);

  const float* ip = in + b * (C * HW) + hw0;
  #pragma unroll 4
  for (int ci = 0; ci < C; ci++) {
    float4 x = *(const float4*)(ip + ci * HW);
    #pragma unroll
    for (int k = 0; k < 16; k++) {
      float wv = wp[(cg * 16 + k) * C + ci];   // uniform -> scalar load
      acc[k].x += wv * x.x; acc[k].y += wv * x.y;
      acc[k].z += wv * x.z; acc[k].w += wv * x.w;
    }
  }
  #pragma unroll
  for (int k = 0; k < 16; k++)
    *(float4*)(out + b * (C * HW) + (cg * 16 + k) * HW + hw0) = acc[k];
}

// ---------------------------------------------------------------------------
// Node kernel: s_new = mix(h0, edge o0) + mix(h1, edge o0+1), written into
// the node's channel slot of d_out.  grid (64 b, 16 co-groups), block 256.
// Each thread: 1x4 output strip for 8 co.
// ---------------------------------------------------------------------------
__global__ __launch_bounds__(256) void node_kernel(
    const float* __restrict__ h0, int h0_bs,
    const float* __restrict__ h1, int h1_bs,
    const float* __restrict__ ws, int o0,
    float* __restrict__ out) {
  __shared__ float p0[PS * PS];
  __shared__ float p1[PS * PS];

  int b = blockIdx.x;
  int cog = blockIdx.y;           // 16 groups of 8 co
  int tid = threadIdx.x;
  int y = tid >> 3;               // 0..31
  int x0 = (tid & 7) * 4;         // 0..28

  // pool/identity alphas for the two edges (uniform scalar loads)
  float a0_0 = ws[ALPHA_OFF + o0 * 5 + 0];
  float a3_0 = ws[ALPHA_OFF + o0 * 5 + 3];
  float a4_0 = ws[ALPHA_OFF + o0 * 5 + 4];
  float a0_1 = ws[ALPHA_OFF + (o0 + 1) * 5 + 0];
  float a3_1 = ws[ALPHA_OFF + (o0 + 1) * 5 + 3];
  float a4_1 = ws[ALPHA_OFF + (o0 + 1) * 5 + 4];

  const float* w3_e0 = ws + W3_OFF  + o0 * (C * C * 9);
  const float* wd_e0 = ws + WD3_OFF + o0 * (C * C * 9);
  const float* w3_e1 = w3_e0 + (C * C * 9);
  const float* wd_e1 = wd_e0 + (C * C * 9);

  const float* h0b = h0 + b * h0_bs;
  const float* h1b = h1 + b * h1_bs;

  float acc[8][4];
  #pragma unroll
  for (int c = 0; c < 8; c++)
    #pragma unroll
    for (int k = 0; k < 4; k++) acc[c][k] = 0.f;

  for (int ci = 0; ci < C; ci++) {
    // ---- stage padded planes for this ci ----
    for (int j = tid; j < PS * PS; j += 256) {
      int py = j / PS, px = j - py * PS;
      int yy = py - 2, xx = px - 2;
      bool v = (yy >= 0) & (yy < H) & (xx >= 0) & (xx < W);
      int off = ci * HW + yy * W + xx;
      p0[j] = v ? h0b[off] : 0.f;
      p1[j] = v ? h1b[off] : 0.f;
    }
    __syncthreads();

    // ---- identity / avg / max terms (only when ci is in this co group) ----
    int cidx = ci - cog * 8;
    if (cidx >= 0 && cidx < 8) {
      #pragma unroll
      for (int k = 0; k < 4; k++) {
        int x = x0 + k;
        int pc = (y + 2) * PS + (x + 2);
        // edge 0 (from h0 plane)
        {
          float cen = p0[pc];
          float s9 = 0.f;
          #pragma unroll
          for (int dy = -1; dy <= 1; dy++)
            #pragma unroll
            for (int dx = -1; dx <= 1; dx++) s9 += p0[pc + dy * PS + dx];
          float mx = cen;
          #pragma unroll
          for (int dy = -1; dy <= 1; dy++)
            #pragma unroll
            for (int dx = -1; dx <= 1; dx++) {
              int yy = y + dy, xx = x + dx;
              if (yy >= 0 && yy < H && xx >= 0 && xx < W)
                mx = fmaxf(mx, p0[pc + dy * PS + dx]);
            }
          acc[cidx][k] += a0_0 * cen + a3_0 * (s9 * (1.f / 9.f)) + a4_0 * mx;
        }
        // edge 1 (from h1 plane)
        {
          float cen = p1[pc];
          float s9 = 0.f;
          #pragma unroll
          for (int dy = -1; dy <= 1; dy++)
            #pragma unroll
            for (int dx = -1; dx <= 1; dx++) s9 += p1[pc + dy * PS + dx];
          float mx = cen;
          #pragma unroll
          for (int dy = -1; dy <= 1; dy++)
            #pragma unroll
            for (int dx = -1; dx <= 1; dx++) {
              int yy = y + dy, xx = x + dx;
              if (yy >= 0 && yy < H && xx >= 0 && xx < W)
                mx = fmaxf(mx, p1[pc + dy * PS + dx]);
            }
          acc[cidx][k] += a0_1 * cen + a3_1 * (s9 * (1.f / 9.f)) + a4_1 * mx;
        }
      }
    }

    // ---- neighborhoods into registers ----
    float A1[3][6], A2[3][8], B1[3][6], B2[3][8];
    #pragma unroll
    for (int r = 0; r < 3; r++)
      #pragma unroll
      for (int c = 0; c < 6; c++) {
        A1[r][c] = p0[(y + 1 + r) * PS + x0 + 1 + c];
        B1[r][c] = p1[(y + 1 + r) * PS + x0 + 1 + c];
      }
    #pragma unroll
    for (int r = 0; r < 3; r++)
      #pragma unroll
      for (int c = 0; c < 8; c++) {
        A2[r][c] = p0[(y + 2 * r) * PS + x0 + c];
        B2[r][c] = p1[(y + 2 * r) * PS + x0 + c];
      }

    // ---- conv taps: 8 co x 9 taps x 4 pos x (2 convs x 2 inputs) ----
    #pragma unroll
    for (int c = 0; c < 8; c++) {
      int co = cog * 8 + c;
      const float* pw3_0 = w3_e0 + (co * C + ci) * 9;
      const float* pwd_0 = wd_e0 + (co * C + ci) * 9;
      const float* pw3_1 = w3_e1 + (co * C + ci) * 9;
      const float* pwd_1 = wd_e1 + (co * C + ci) * 9;
      #pragma unroll
      for (int t = 0; t < 9; t++) {
        int ky = t / 3, kx = t - ky * 3;
        float w3a = pw3_0[t], wda = pwd_0[t];
        float w3b = pw3_1[t], wdb = pwd_1[t];
        #pragma unroll
        for (int k = 0; k < 4; k++) {
          acc[c][k] += w3a * A1[ky][k + kx];
          acc[c][k] += wda * A2[ky][k + 2 * kx];
          acc[c][k] += w3b * B1[ky][k + kx];
          acc[c][k] += wdb * B2[ky][k + 2 * kx];
        }
      }
    }
    __syncthreads();
  }

  // ---- write out (channel slot already folded into `out`) ----
  #pragma unroll
  for (int c = 0; c < 8; c++) {
    float* op = out + b * (OUTC * HW) + (cog * 8 + c) * HW + y * W + x0;
    *(float4*)op = make_float4(acc[c][0], acc[c][1], acc[c][2], acc[c][3]);
  }
}

// ---------------------------------------------------------------------------
// skip_input -> out channels [512,640) and second tuple output
// ---------------------------------------------------------------------------
__global__ __launch_bounds__(256) void skip_kernel(
    const float* __restrict__ skip, float* __restrict__ dout) {
  int i = blockIdx.x * 256 + threadIdx.x;     // over NSKIP/4 float4s
  if (i < NSKIP / 4) {
    float4 v = ((const float4*)skip)[i];
    int e = i * 4;
    int b = e >> 17;                 // / (C*HW)
    int rem = e & (C * HW - 1);
    *(float4*)(dout + b * (OUTC * HW) + 512 * HW + rem) = v;
    *(float4*)(dout + B * (OUTC * HW) + e) = v;
  }
}

// ---------------------------------------------------------------------------
extern "C" void kernel_launch(void* const* d_in, const int* in_sizes, int n_in,
                              void* d_out, int out_size, void* d_ws, size_t ws_size,
                              hipStream_t stream) {
  const float* input0 = (const float*)d_in[0];
  const float* input1 = (const float*)d_in[1];
  const float* skip   = (const float*)d_in[2];
  const float* wpre0  = (const float*)d_in[3];
  const float* wpre1  = (const float*)d_in[4];
  const float* wconv3 = (const float*)d_in[5];
  const float* wdil3  = (const float*)d_in[6];
  const float* alphas = (const float*)d_in[7];
  float* out = (float*)d_out;
  float* ws  = (float*)d_ws;   // needs ~76.5 MB

  prep_kernel<<<512, 256, 0, stream>>>(alphas, wconv3, wdil3, ws);
  pre_kernel<<<dim3(B, 8, 2), 256, 0, stream>>>(input0, input1, wpre0, wpre1, ws);

  const float* s0 = ws + S0_OFF;
  const float* s1 = ws + S1_OFF;
  const int wsb = C * HW;       // batch stride of ws-resident states
  const int ob  = OUTC * HW;    // batch stride of d_out-resident states

  // node0: s2 = mix(s0, e0) + mix(s1, e1)
  node_kernel<<<dim3(B, 16), 256, 0, stream>>>(s0, wsb, s1, wsb, ws, 0, out + 0 * C * HW);
  // node1: s3 = mix(s1, e2) + mix(s2, e3)
  node_kernel<<<dim3(B, 16), 256, 0, stream>>>(s1, wsb, out + 0 * C * HW, ob, ws, 2, out + 1 * C * HW);
  // node2: s4 = mix(s2, e4) + mix(s3, e5)
  node_kernel<<<dim3(B, 16), 256, 0, stream>>>(out + 0 * C * HW, ob, out + 1 * C * HW, ob, ws, 4, out + 2 * C * HW);
  // node3: s5 = mix(s3, e6) + mix(s4, e7)
  node_kernel<<<dim3(B, 16), 256, 0, stream>>>(out + 1 * C * HW, ob, out + 2 * C * HW, ob, ws, 6, out + 3 * C * HW);

  skip_kernel<<<(NSKIP / 4 + 255) / 256, 256, 0, stream>>>(skip, out);
}